// Round 5
// baseline (441.557 us; speedup 1.0000x reference)
//
#include <hip/hip_runtime.h>
#include <stdint.h>

typedef __attribute__((ext_vector_type(8))) short short8;
typedef __attribute__((ext_vector_type(4))) float f32x4;

constexpr int T_ = 4;
constexpr int BNTOT = 32768; // B*N

__device__ __forceinline__ void gload_lds16(const void* g, void* lds) {
    __builtin_amdgcn_global_load_lds(
        (const __attribute__((address_space(1))) void*)g,
        (__attribute__((address_space(3))) void*)lds, 16, 0, 0);
}

// f32 -> bf16 (RNE)
__device__ __forceinline__ uint32_t bf1(float f) {
    uint32_t x = __builtin_bit_cast(uint32_t, f);
    return (x + 0x7FFFu + ((x >> 16) & 1u)) >> 16;
}
__device__ __forceinline__ uint32_t pk(float lo, float hi) {
    return bf1(lo) | (bf1(hi) << 16);
}

__global__ __launch_bounds__(256)
void cvt_bf16(const float* __restrict__ in, ushort* __restrict__ out) {
    const size_t i = ((size_t)blockIdx.x * 256 + threadIdx.x) * 8;
    const float4 a = *(const float4*)(in + i);
    const float4 b = *(const float4*)(in + i + 4);
    uint4 o;
    o.x = pk(a.x, a.y); o.y = pk(a.z, a.w);
    o.z = pk(b.x, b.y); o.w = pk(b.z, b.w);
    *(uint4*)(out + i) = o;
}

// Fused bf16-MFMA GEMM (C = A @ W^T) + multi-step LIF over T=4.
// A: bf16 [T][BNTOT][K]; W: f32 [NOUT][K]; Out: [T][BNTOT][NOUT]
// MODE 0: out bf16 spikes; 1: out bf16 h*(1-s) (h == A); 2: out f32 spikes.
// Block: 256 thr = 4 waves; wave w owns t=w, computes 64x64 tile.
// BK=32, LDS=40KB -> 4 blocks/CU (16 waves/CU): co-resident independent
// blocks hide each other's barrier drains (the round-3 stall).
template <int MODE, int K, int NOUT>
__global__ __launch_bounds__(256, 4)
void lif_mfma(const ushort* __restrict__ A,
              const float* __restrict__ W,
              void* __restrict__ Out)
{
    // LDS map: A dbuf [2][4t][64r][4g][16B] = 32768 (granule g' = g ^ ((row>>1)&3))
    //          B dbuf [2][64c][4g][16B]     =  8192 at 32768
    // epilogue Y [4t][64r][32c] f32 = 32768 aliases A region.
    __shared__ __align__(16) char smem[40960];

    constexpr int NS = K / 32;
    constexpr int NCOLT = NOUT / 64;

    const int tid = threadIdx.x;
    const int l   = tid & 63;
    const int w   = tid >> 6;          // wave = time step

    // XCD-bijective swizzle: xcd=id&7 owns a contiguous row-tile chunk;
    // col tiles sweep fastest so the A row-panel stays in that XCD's L2.
    const int id  = blockIdx.x;
    const int xcd = id & 7;
    const int j_  = id >> 3;
    const int row0 = (xcd * 64 + j_ / NCOLT) * 64;
    const int col0 = (j_ % NCOLT) * 64;

    // fragment-read constants: lane l reads row/col (l&15), k-granule (l>>4),
    // at swizzled slot (l>>4) ^ (((l&15)>>1)&3)
    const int rby = (l & 15) * 64;
    const int gp  = ((l >> 4) ^ ((l >> 1) & 3)) << 4;

    f32x4 acc[4][4];
#pragma unroll
    for (int m = 0; m < 4; ++m)
#pragma unroll
        for (int n = 0; n < 4; ++n) acc[m][n] = (f32x4)0.f;

    // ---- A staging: 4 gload_lds/wave/tile, pre-swizzled per-lane source ----
    // gload j writes rows j*16+(l>>2), slot l&3; content granule must be
    // (l&3) ^ key(row); key(row)=((row>>1)&3) -> (l&3)^((l>>3)&3) (j*8%4==0).
    const int a_gsrc = (l & 3) ^ ((l >> 3) & 3);
    const ushort* a_base = A + ((size_t)(w * BNTOT + row0) + (l >> 2)) * K + a_gsrc * 8;

    // ---- B staging: reg+cvt; thread -> col tid>>2, slot tid&3 ----
    const int b_col  = tid >> 2;
    const int b_gsrc = (tid & 3) ^ ((tid >> 3) & 3);
    const float* w_base = W + (size_t)(col0 + b_col) * K + b_gsrc * 8;

    auto stageA = [&](int s, int buf) {
        const ushort* ap = a_base + s * 32;
        char* ad = smem + buf * 16384 + w * 4096;
#pragma unroll
        for (int j = 0; j < 4; ++j)
            gload_lds16(ap + (size_t)j * 16 * K, ad + j * 1024);
    };
    auto writeB = [&](const float4& f0, const float4& f1, int buf) {
        uint4 o;
        o.x = pk(f0.x, f0.y); o.y = pk(f0.z, f0.w);
        o.z = pk(f1.x, f1.y); o.w = pk(f1.z, f1.w);
        *(uint4*)(smem + 32768 + buf * 4096 + b_col * 64 + (tid & 3) * 16) = o;
    };

    // ---- prologue ----
    {
        const float4 f0 = *(const float4*)(w_base);
        const float4 f1 = *(const float4*)(w_base + 4);
        stageA(0, 0);
        writeB(f0, f1, 0);
    }
    __syncthreads();

    int buf = 0;
    for (int s = 0; s < NS; ++s) {
        const bool more = (s + 1 < NS);
        float4 f0, f1;
        if (more) { // issue next-tile loads early; latency hides under MFMA
            const float* wp = w_base + (s + 1) * 32;
            f0 = *(const float4*)(wp);
            f1 = *(const float4*)(wp + 4);
            stageA(s + 1, buf ^ 1);
        }
        {
            const char* at = smem + buf * 16384 + w * 4096;
            const char* bt = smem + 32768 + buf * 4096;
            short8 af[4], bfr[4];
#pragma unroll
            for (int m = 0; m < 4; ++m)
                af[m] = *(const short8*)(at + m * 1024 + rby + gp);
#pragma unroll
            for (int n = 0; n < 4; ++n)
                bfr[n] = *(const short8*)(bt + n * 1024 + rby + gp);
#pragma unroll
            for (int m = 0; m < 4; ++m)
#pragma unroll
                for (int n = 0; n < 4; ++n)
                    acc[m][n] = __builtin_amdgcn_mfma_f32_16x16x32_bf16(
                        af[m], bfr[n], acc[m][n], 0, 0, 0);
        }
        if (more) writeB(f0, f1, buf ^ 1); // write-late
        __syncthreads();
        buf ^= 1;
    }

    // ---- epilogue: two 32-col halves; Y[4t][64][32] f32 in LDS ----
    float* Y = (float*)smem;
#pragma unroll
    for (int half = 0; half < 2; ++half) {
        // write this half's acc (C/D map: col=l&15(+n*16), row=(l>>4)*4+j(+m*16))
#pragma unroll
        for (int nn = 0; nn < 2; ++nn) {
            const int n = half * 2 + nn;
#pragma unroll
            for (int m = 0; m < 4; ++m)
#pragma unroll
                for (int j = 0; j < 4; ++j) {
                    const int row = m * 16 + (l >> 4) * 4 + j;
                    const int cl  = nn * 16 + (l & 15);
                    const int colp = cl ^ (((row >> 2) & 1) << 4);
                    Y[w * 2048 + row * 32 + colp] = acc[m][n][j];
                }
        }
        __syncthreads();
        // scan: unit = (row, col-pair); 1024 units / 256 thr = 4 each
#pragma unroll
        for (int u4 = 0; u4 < 4; ++u4) {
            const int u   = u4 * 256 + tid;
            const int row = u >> 4;
            const int cp  = (u & 15) * 2;
            const int colp = cp ^ (((row >> 2) & 1) << 4);
            float v0 = 0.f, v1 = 0.f;
#pragma unroll
            for (int t = 0; t < T_; ++t) {
                const float2 y = *(const float2*)&Y[t * 2048 + row * 32 + colp];
                v0 = 0.5f * (v0 + y.x);
                v1 = 0.5f * (v1 + y.y);
                const bool s0 = (v0 >= 1.f), s1 = (v1 >= 1.f);
                v0 = s0 ? 0.f : v0;
                v1 = s1 ? 0.f : v1;
                const size_t orow = (size_t)(t * BNTOT + row0 + row);
                const int oc = col0 + half * 32 + cp;
                if (MODE == 0) {
                    uint32_t uo = (s0 ? 0x3F80u : 0u) | (s1 ? 0x3F800000u : 0u);
                    *(uint32_t*)((ushort*)Out + orow * NOUT + oc) = uo;
                } else if (MODE == 1) {
                    const uint32_t h = *(const uint32_t*)(A + orow * K + oc);
                    const uint32_t msk = (s0 ? 0u : 0xFFFFu) | (s1 ? 0u : 0xFFFF0000u);
                    *(uint32_t*)((ushort*)Out + orow * NOUT + oc) = h & msk;
                } else {
                    float2 o;
                    o.x = s0 ? 1.f : 0.f;
                    o.y = s1 ? 1.f : 0.f;
                    *(float2*)((float*)Out + orow * NOUT + oc) = o;
                }
            }
        }
        __syncthreads();
    }
}

extern "C" void kernel_launch(void* const* d_in, const int* in_sizes, int n_in,
                              void* d_out, int out_size, void* d_ws, size_t ws_size,
                              hipStream_t stream)
{
    const float* x     = (const float*)d_in[0];  // [4,32,1024,256]
    const float* w_in  = (const float*)d_in[1];  // [512,256]
    const float* w_h   = (const float*)d_in[2];  // [2,512,512]
    const float* w_out = (const float*)d_in[3];  // [256,512]

    // xbf = d_out[0:64MiB]; hA = d_ws[0:128MiB]; hB = d_out[0:128MiB]
    ushort* xbf = (ushort*)d_out;
    ushort* hA  = (ushort*)d_ws;
    ushort* hB  = (ushort*)d_out;
    float*  out = (float*)d_out;

    cvt_bf16<<<16384, 256, 0, stream>>>(x, xbf);

    lif_mfma<0, 256, 512><<<8 * 512, 256, 0, stream>>>(xbf, w_in, hA);
    lif_mfma<1, 512, 512><<<8 * 512, 256, 0, stream>>>(hA, w_h, hB);
    lif_mfma<1, 512, 512><<<8 * 512, 256, 0, stream>>>(hB, w_h + 512 * 512, hA);
    lif_mfma<2, 512, 256><<<4 * 512, 256, 0, stream>>>(hA, w_out, out);
}

// Round 6
// 409.529 us; speedup vs baseline: 1.0782x; 1.0782x over previous
//
#include <hip/hip_runtime.h>
#include <stdint.h>

typedef __attribute__((ext_vector_type(8))) short short8;
typedef __attribute__((ext_vector_type(4))) float f32x4;

constexpr int T_ = 4;
constexpr int BNTOT = 32768; // B*N

// f32 -> bf16 (RNE)
__device__ __forceinline__ uint32_t bf1(float f) {
    uint32_t x = __builtin_bit_cast(uint32_t, f);
    return (x + 0x7FFFu + ((x >> 16) & 1u)) >> 16;
}
__device__ __forceinline__ uint32_t pk(float lo, float hi) {
    return bf1(lo) | (bf1(hi) << 16);
}

// x [T][BN][256] f32 -> MFMA-fragment-tiled bf16 [T*BN/16][32][16][8]
// unit g = (bt*16 + r)*32 + kg  (kg fastest => coalesced 32B reads)
__global__ __launch_bounds__(256)
void cvt_tiled(const float* __restrict__ in, ushort* __restrict__ out) {
    const int g   = blockIdx.x * 256 + threadIdx.x;
    const int kg  = g & 31;
    const int r   = (g >> 5) & 15;
    const int bt  = g >> 9;            // t*(BN/16)+bt  (rows are contiguous)
    const float* src = in + ((size_t)(bt * 16 + r)) * 256 + kg * 8;
    const float4 a = *(const float4*)src;
    const float4 b = *(const float4*)(src + 4);
    uint4 o;
    o.x = pk(a.x, a.y); o.y = pk(a.z, a.w);
    o.z = pk(b.x, b.y); o.w = pk(b.z, b.w);
    *(uint4*)(out + ((size_t)(bt * 32 + kg)) * 128 + r * 8) = o;
}

// Fused bf16-MFMA GEMM (C = A @ W^T) + multi-step LIF over T=4.
// A: tiled bf16 [T][BN/16][K/8][16][8]  (fragment-direct, NO LDS for A)
// W: f32 [NOUT][K]
// Out: MODE 0/1 tiled bf16 [T][BN/16][NOUT/8][16][8]; MODE 2 f32 [T][BN][NOUT]
// MODE 0: spikes; 1: h*(1-s) (h == A); 2: f32 spikes.
// Block: 4 waves; wave w owns t=w, 64x64 tile. BK=32.
// K-loop: A frags global->reg pipelined (compiler counted-vmcnt, no drain);
// B staged f32->bf16 into 2 LDS bufs; raw s_barrier + lgkmcnt(0) only.
template <int MODE, int K, int NOUT>
__global__ __launch_bounds__(256, 3)
void lif_mfma(const ushort* __restrict__ A,
              const float* __restrict__ W,
              void* __restrict__ Out)
{
    // LDS: B bufs [2][64c][4 slots][16B] = 8192 ; Y [4][64][32] f32 = 32768
    __shared__ __align__(16) char smem[8192 + 32768];

    constexpr int NS = K / 32;
    constexpr int NCOLT = NOUT / 64;

    const int tid = threadIdx.x;
    const int l   = tid & 63;
    const int w   = tid >> 6;          // wave = time step

    // XCD-bijective swizzle: xcd owns contiguous row-tile chunk, cols fastest.
    const int id  = blockIdx.x;
    const int xcd = id & 7;
    const int j_  = id >> 3;
    const int row0 = (xcd * 64 + j_ / NCOLT) * 64;
    const int col0 = (j_ % NCOLT) * 64;

    // B fragment read offsets (XOR-swizzled, proven 0-conflict in r4)
    const int rby = (l & 15) * 64;
    const int gp  = ((l >> 4) ^ ((l >> 1) & 3)) << 4;

    // A tiled lane base: elem = ((t*(BN/16)+bt)*(K/8)+kg)*128 + r*8
    const ushort* abase = A +
        ((size_t)(w * (BNTOT / 16) + (row0 >> 4)) * (K / 8) + (l >> 4)) * 128 +
        (l & 15) * 8;
    // frag (m, s): abase + m*K*16 + s*512   [elems]

    // B staging: thread -> col tid>>2, slot tid&3; content granule slot^key(col)
    const int b_col = tid >> 2;
    const float* w_base = W + (size_t)(col0 + b_col) * K +
                          ((tid & 3) ^ ((tid >> 3) & 3)) * 8;
    const int bwo = b_col * 64 + (tid & 3) * 16;

    f32x4 acc[4][4];
#pragma unroll
    for (int m = 0; m < 4; ++m)
#pragma unroll
        for (int n = 0; n < 4; ++n) acc[m][n] = (f32x4)0.f;

    auto loadA = [&](int s, short8 af[4]) {
#pragma unroll
        for (int m = 0; m < 4; ++m)
            af[m] = *(const short8*)(abase + (size_t)m * (K * 16) + s * 512);
    };
    auto loadB = [&](int s, float4& f0, float4& f1) {
        const float* wp = w_base + s * 32;
        f0 = *(const float4*)wp;
        f1 = *(const float4*)(wp + 4);
    };
    auto writeB = [&](const float4& f0, const float4& f1, char* buf) {
        uint4 o;
        o.x = pk(f0.x, f0.y); o.y = pk(f0.z, f0.w);
        o.z = pk(f1.x, f1.y); o.w = pk(f1.z, f1.w);
        *(uint4*)(buf + bwo) = o;
    };
    auto compute = [&](const short8 af[4], const char* buf) {
        short8 bfr[4];
#pragma unroll
        for (int n = 0; n < 4; ++n)
            bfr[n] = *(const short8*)(buf + n * 1024 + rby + gp);
#pragma unroll
        for (int m = 0; m < 4; ++m)
#pragma unroll
            for (int n = 0; n < 4; ++n)
                acc[m][n] = __builtin_amdgcn_mfma_f32_16x16x32_bf16(
                    af[m], bfr[n], acc[m][n], 0, 0, 0);
    };

    char* const bs0 = smem;
    char* const bs1 = smem + 4096;

    short8 aEv[4], aOd[4];
    float4 bEv0, bEv1, bOd0, bOd1;

    // prologue: step 0 into Ev / bs0
    loadA(0, aEv);
    loadB(0, bEv0, bEv1);
    writeB(bEv0, bEv1, bs0);
    asm volatile("s_waitcnt lgkmcnt(0)\n\ts_barrier" ::: "memory");

    // main loop: 2 steps/iter (named reg sets; no vmcnt drain anywhere)
    for (int s = 0; s < NS; s += 2) {
        const int s1 = (s + 1 < NS) ? s + 1 : s;   // tail clamp (harmless reload)
        loadA(s1, aOd);
        loadB(s1, bOd0, bOd1);
        compute(aEv, bs0);                  // MFMAs issue before writeB's wait
        writeB(bOd0, bOd1, bs1);
        asm volatile("s_waitcnt lgkmcnt(0)\n\ts_barrier" ::: "memory");

        const int s2 = (s + 2 < NS) ? s + 2 : s;
        loadA(s2, aEv);
        loadB(s2, bEv0, bEv1);
        compute(aOd, bs1);
        writeB(bEv0, bEv1, bs0);
        asm volatile("s_waitcnt lgkmcnt(0)\n\ts_barrier" ::: "memory");
    }

    // ---- epilogue: two 32-col halves; Y[4t][64][32] f32 in LDS ----
    float* Y = (float*)(smem + 8192);
#pragma unroll
    for (int half = 0; half < 2; ++half) {
#pragma unroll
        for (int nn = 0; nn < 2; ++nn) {
            const int n = half * 2 + nn;
#pragma unroll
            for (int m = 0; m < 4; ++m)
#pragma unroll
                for (int j = 0; j < 4; ++j) {
                    const int row = m * 16 + (l >> 4) * 4 + j;
                    const int cl  = nn * 16 + (l & 15);
                    const int colp = cl ^ (((row >> 2) & 1) << 4);
                    Y[w * 2048 + row * 32 + colp] = acc[m][n][j];
                }
        }
        __syncthreads();
        // scan: unit = (row, col-pair); 1024 units / 256 thr
#pragma unroll
        for (int u4 = 0; u4 < 4; ++u4) {
            const int u   = u4 * 256 + tid;
            const int row = u >> 4;
            const int cp  = (u & 15) * 2;
            const int colp = cp ^ (((row >> 2) & 1) << 4);
            float v0 = 0.f, v1 = 0.f;
#pragma unroll
            for (int t = 0; t < T_; ++t) {
                const float2 y = *(const float2*)&Y[t * 2048 + row * 32 + colp];
                v0 = 0.5f * (v0 + y.x);
                v1 = 0.5f * (v1 + y.y);
                const bool s0 = (v0 >= 1.f), s1 = (v1 >= 1.f);
                v0 = s0 ? 0.f : v0;
                v1 = s1 ? 0.f : v1;
                const int grow = row0 + row;
                const int c    = col0 + half * 32 + cp;
                if (MODE == 2) {
                    float2 o;
                    o.x = s0 ? 1.f : 0.f;
                    o.y = s1 ? 1.f : 0.f;
                    *(float2*)((float*)Out + ((size_t)(t * BNTOT + grow)) * NOUT + c) = o;
                } else {
                    const size_t tb = ((size_t)(t * (BNTOT / 16) + (grow >> 4)) *
                                       (NOUT / 8) + (c >> 3)) * 128 + (grow & 15) * 8 + (c & 7);
                    if (MODE == 0) {
                        uint32_t uo = (s0 ? 0x3F80u : 0u) | (s1 ? 0x3F800000u : 0u);
                        *(uint32_t*)((ushort*)Out + tb) = uo;
                    } else { // MODE 1: gate h*(1-s); h tiled with K/8 == NOUT/8
                        const uint32_t h = *(const uint32_t*)(A + tb);
                        const uint32_t msk = (s0 ? 0u : 0xFFFFu) | (s1 ? 0u : 0xFFFF0000u);
                        *(uint32_t*)((ushort*)Out + tb) = h & msk;
                    }
                }
            }
        }
        __syncthreads();
    }
}

extern "C" void kernel_launch(void* const* d_in, const int* in_sizes, int n_in,
                              void* d_out, int out_size, void* d_ws, size_t ws_size,
                              hipStream_t stream)
{
    const float* x     = (const float*)d_in[0];  // [4,32,1024,256]
    const float* w_in  = (const float*)d_in[1];  // [512,256]
    const float* w_h   = (const float*)d_in[2];  // [2,512,512]
    const float* w_out = (const float*)d_in[3];  // [256,512]

    // xbf (tiled, 67MB) = d_out; hA (tiled, 134MB) = d_ws; hB (tiled, 134MB) = d_out
    ushort* xbf = (ushort*)d_out;
    ushort* hA  = (ushort*)d_ws;
    ushort* hB  = (ushort*)d_out;
    float*  out = (float*)d_out;

    cvt_tiled<<<16384, 256, 0, stream>>>(x, xbf);

    lif_mfma<0, 256, 512><<<8 * 512, 256, 0, stream>>>(xbf, w_in, hA);
    lif_mfma<1, 512, 512><<<8 * 512, 256, 0, stream>>>(hA, w_h, hB);
    lif_mfma<1, 512, 512><<<8 * 512, 256, 0, stream>>>(hB, w_h + 512 * 512, hA);
    lif_mfma<2, 512, 256><<<4 * 512, 256, 0, stream>>>(hA, w_out, out);
}

// Round 7
// 348.653 us; speedup vs baseline: 1.2665x; 1.1746x over previous
//
#include <hip/hip_runtime.h>
#include <stdint.h>

typedef __attribute__((ext_vector_type(8))) short short8;
typedef __attribute__((ext_vector_type(4))) float f32x4;

constexpr int T_ = 4;
constexpr int BNTOT = 32768; // B*N

// f32 -> bf16 (RNE)
__device__ __forceinline__ uint32_t bf1(float f) {
    uint32_t x = __builtin_bit_cast(uint32_t, f);
    return (x + 0x7FFFu + ((x >> 16) & 1u)) >> 16;
}
__device__ __forceinline__ uint32_t pk(float lo, float hi) {
    return bf1(lo) | (bf1(hi) << 16);
}

// 8 u8 {0,1} -> 8 bf16 {0,1.0}: per dword, place byte 2k at b0 and 2k+1 at b2
// (v_perm), then *0x3F80 turns each 0/1 into bf16 0/1.0 in both halves.
__device__ __forceinline__ short8 expand8(uint2 r) {
    uint4 o;
    o.x = __builtin_amdgcn_perm(0u, r.x, 0x0C010C00u) * 0x3F80u;
    o.y = __builtin_amdgcn_perm(0u, r.x, 0x0C030C02u) * 0x3F80u;
    o.z = __builtin_amdgcn_perm(0u, r.y, 0x0C010C00u) * 0x3F80u;
    o.w = __builtin_amdgcn_perm(0u, r.y, 0x0C030C02u) * 0x3F80u;
    return __builtin_bit_cast(short8, o);
}

// x [T*BN][256] f32 -> MFMA-fragment-tiled bf16 [T*BN/16][32][16][8]
__global__ __launch_bounds__(256)
void cvt_tiled(const float* __restrict__ in, ushort* __restrict__ out) {
    const int g  = blockIdx.x * 256 + threadIdx.x;
    const int kg = g & 31;
    const int r  = (g >> 5) & 15;
    const int bt = g >> 9;
    const float* src = in + ((size_t)(bt * 16 + r)) * 256 + kg * 8;
    const float4 a = *(const float4*)src;
    const float4 b = *(const float4*)(src + 4);
    uint4 o;
    o.x = pk(a.x, a.y); o.y = pk(a.z, a.w);
    o.z = pk(b.x, b.y); o.w = pk(b.z, b.w);
    *(uint4*)(out + ((size_t)(bt * 32 + kg)) * 128 + r * 8) = o;
}

// Fused bf16-MFMA GEMM (C = A @ W^T) + multi-step LIF over T=4.
// A: MODE 0: tiled bf16 [T][BN/16][K/8][16][8]; MODE 1/2: tiled u8 (same geom).
// W: f32 [NOUT][K]  (converted+staged to LDS once per block)
// Out: MODE 0/1: tiled u8 [T][BN/16][NOUT/8][16][8]; MODE 2: f32 [T][BN][NOUT]
// Block: 4 waves; wave w owns rows [row0+16w, +16) for ALL 4 t (t-scan is
// thread-local). K-loop has NO barriers: B immutable in LDS, A direct-to-reg
// with depth-1 named-register pipeline (compiler counted vmcnt).
template <int MODE, int K, int NOUT>
__global__ __launch_bounds__(256, 2)
void lif_mfma(const void* __restrict__ Av,
              const float* __restrict__ W,
              void* __restrict__ Out)
{
    constexpr int NS = K / 32;      // K-steps
    constexpr int KG = K / 8;       // k-granules
    constexpr int NCOLT = NOUT / 64;
    __shared__ __align__(16) char smem[NS * 4096]; // B panel: 4 nfrag x NS x 1KB

    const int tid = threadIdx.x;
    const int l   = tid & 63;
    const int w   = tid >> 6;

    // XCD-bijective swizzle: xcd owns contiguous row-tile chunk, cols fastest.
    const int id  = blockIdx.x;
    const int xcd = id & 7;
    const int j_  = id >> 3;
    const int row0 = (xcd * 64 + j_ / NCOLT) * 64;
    const int col0 = (j_ % NCOLT) * 64;

    // ---- stage B col-panel (64 x K) f32 -> bf16 frag-tiled, XOR-swizzled ----
    {
        constexpr int ITERS = 64 * KG / 256;
#pragma unroll
        for (int i = 0; i < ITERS; ++i) {
            const int idx = i * 256 + tid;
            const int c   = idx / KG;   // col in panel (slow: coalesced W reads)
            const int kg  = idx % KG;
            const float* wp = W + (size_t)(col0 + c) * K + kg * 8;
            const float4 f0 = *(const float4*)wp;
            const float4 f1 = *(const float4*)(wp + 4);
            uint4 o;
            o.x = pk(f0.x, f0.y); o.y = pk(f0.z, f0.w);
            o.z = pk(f1.x, f1.y); o.w = pk(f1.z, f1.w);
            const int s = kg >> 2, g = kg & 3;
            *(uint4*)(smem + ((c >> 4) * NS + s) * 1024 + (c & 15) * 64 +
                      ((g ^ ((c >> 1) & 3)) * 16)) = o;
        }
    }
    __syncthreads();   // the ONLY block-wide barrier

    const char* bbase = smem + (l & 15) * 64 + (((l >> 4) ^ ((l >> 1) & 3)) * 16);
    const int rb = (row0 >> 4) + w;   // this wave's 16-row block index

    f32x4 acc[T_][4];
#pragma unroll
    for (int t = 0; t < T_; ++t)
#pragma unroll
        for (int n = 0; n < 4; ++n) acc[t][n] = (f32x4)0.f;

    // A frag unit index (128-elem/byte units): (t*(BN/16)+rb)*KG + s*4 + (l>>4)
    size_t aunit[T_];
#pragma unroll
    for (int t = 0; t < T_; ++t)
        aunit[t] = ((size_t)(t * (BNTOT / 16) + rb)) * KG + (l >> 4);

    auto loadAb = [&](int s, short8 a[T_]) {
#pragma unroll
        for (int t = 0; t < T_; ++t)
            a[t] = *(const short8*)((const ushort*)Av +
                     (aunit[t] + s * 4) * 128 + (l & 15) * 8);
    };
    auto loadAu = [&](int s, uint2 a[T_]) {
#pragma unroll
        for (int t = 0; t < T_; ++t)
            a[t] = *(const uint2*)((const uint8_t*)Av +
                     (aunit[t] + s * 4) * 128 + (l & 15) * 8);
    };
    auto stepB = [&](const short8 a[T_], int s) {
        short8 bfr[4];
#pragma unroll
        for (int n = 0; n < 4; ++n)
            bfr[n] = *(const short8*)(bbase + (n * NS + s) * 1024);
#pragma unroll
        for (int t = 0; t < T_; ++t)
#pragma unroll
            for (int n = 0; n < 4; ++n)
                acc[t][n] = __builtin_amdgcn_mfma_f32_16x16x32_bf16(
                    a[t], bfr[n], acc[t][n], 0, 0, 0);
    };
    auto stepU = [&](const uint2 a[T_], int s) {
        short8 bfr[4];
#pragma unroll
        for (int n = 0; n < 4; ++n)
            bfr[n] = *(const short8*)(bbase + (n * NS + s) * 1024);
#pragma unroll
        for (int t = 0; t < T_; ++t) {
            const short8 af = expand8(a[t]);
#pragma unroll
            for (int n = 0; n < 4; ++n)
                acc[t][n] = __builtin_amdgcn_mfma_f32_16x16x32_bf16(
                    af, bfr[n], acc[t][n], 0, 0, 0);
        }
    };

    // depth-1 pipelined K-loop, named register sets, NO barriers
    if constexpr (MODE == 0) {
        short8 a0[T_], a1[T_];
        loadAb(0, a0);
        for (int s = 0; s < NS; s += 2) {
            loadAb(s + 1, a1);
            stepB(a0, s);
            loadAb(s + 2 < NS ? s + 2 : 0, a0);
            stepB(a1, s + 1);
        }
    } else {
        uint2 a0[T_], a1[T_];
        loadAu(0, a0);
        for (int s = 0; s < NS; s += 2) {
            loadAu(s + 1, a1);
            stepU(a0, s);
            loadAu(s + 2 < NS ? s + 2 : 0, a0);
            stepU(a1, s + 1);
        }
    }

    // ---- epilogue: thread-local LIF t-scan (no LDS, no barrier) ----
    // C/D map: col = l&15 (+n*16), row = (l>>4)*4 + j (+ wave's 16-row slice)
#pragma unroll
    for (int n = 0; n < 4; ++n) {
#pragma unroll
        for (int j = 0; j < 4; ++j) {
            const int rl   = (l >> 4) * 4 + j;
            const int grow = row0 + w * 16 + rl;
            const int c    = col0 + n * 16 + (l & 15);
            float v = 0.f;
#pragma unroll
            for (int t = 0; t < T_; ++t) {
                v = 0.5f * (v + acc[t][n][j]);
                const bool sp = (v >= 1.f);
                if (sp) v = 0.f;
                if constexpr (MODE == 2) {
                    ((float*)Out)[((size_t)(t * BNTOT + grow)) * NOUT + c] =
                        sp ? 1.f : 0.f;
                } else {
                    const size_t tb =
                        ((size_t)(t * (BNTOT / 16) + (grow >> 4)) * (NOUT / 8) +
                         (c >> 3)) * 128 + rl * 8 + (c & 7);
                    if constexpr (MODE == 0) {
                        ((uint8_t*)Out)[tb] = sp ? 1 : 0;
                    } else { // gate: h * (1 - s); h == A, same tiled geometry
                        const uint8_t h = ((const uint8_t*)Av)[tb];
                        ((uint8_t*)Out)[tb] = sp ? 0 : h;
                    }
                }
            }
        }
    }
}

extern "C" void kernel_launch(void* const* d_in, const int* in_sizes, int n_in,
                              void* d_out, int out_size, void* d_ws, size_t ws_size,
                              hipStream_t stream)
{
    const float* x     = (const float*)d_in[0];  // [4,32,1024,256]
    const float* w_in  = (const float*)d_in[1];  // [512,256]
    const float* w_h   = (const float*)d_in[2];  // [2,512,512]
    const float* w_out = (const float*)d_in[3];  // [256,512]

    // xbf (tiled bf16 x, 67MB) = d_out[0:67MB] (dead before L4 writes out)
    // hA u8 = d_ws[0:67.1MB), hB u8 = d_ws[67.1:134.2MB) — exactly 128 MiB
    ushort*  xbf = (ushort*)d_out;
    uint8_t* hA  = (uint8_t*)d_ws;
    uint8_t* hB  = hA + (size_t)T_ * BNTOT * 512;
    float*   out = (float*)d_out;

    cvt_tiled<<<16384, 256, 0, stream>>>(x, xbf);

    lif_mfma<0, 256, 512><<<4096, 256, 0, stream>>>(xbf, w_in, hA);
    lif_mfma<1, 512, 512><<<4096, 256, 0, stream>>>(hA, w_h, hB);
    lif_mfma<1, 512, 512><<<4096, 256, 0, stream>>>(hB, w_h + 512 * 512, hA);
    lif_mfma<2, 512, 256><<<2048, 256, 0, stream>>>(hA, w_out, out);
}